// Round 4
// baseline (6805.706 us; speedup 1.0000x reference)
//
#include <hip/hip_runtime.h>
#include <hip/hip_bf16.h>
#include <hip/hip_fp16.h>
#include <stdint.h>

// Seq2Seq LSTM: B=4096, H=512, E=128, 32 enc + 32 dec steps, V_tgt=128.
// Round 14: MULTI-STEP LAUNCHES + SLOT-ROTATION FRESHNESS.
// R13 (in-kernel pipelining) was NULL -> per-step cost is launch overhead +
// kernel-boundary L2 invalidation (W/proj/c refill every step) + c RMW.
// This round: 7 lstm launches instead of 64. Within a launch:
//  - h_t written to a FRESH slot each step via sc0+sc1 write-through stores
//    (committed at L3); arrive-atomic is RELEASE (wbl2) as belt+suspenders.
//  - consumers read h with the normal fast global_load_lds path: their L2
//    is provably COLD for that slot (each slot written once then read once
//    per launch, write-before-read; kernel boundary flushes between).
//  - W/proj stay L2-cached across steps; c_state + enc h-carry in REGISTERS.
//  - per-m-tile arrival counters (32 blocks) instead of global drain;
//    CU-skew maps 4 different m-chains per CU so spins hide under MFMA.
// GEMM tiles/swizzles/epilogue math identical to R10 -> absmax unchanged.
// Enc = 3 launches (12,12,8 steps: 12-slot freshness window); dec = 4x8
// (ring-10 + outproj contract preserved; enc final h = slot 31%12 = 7).

#define NB     4096
#define SSRC   32
#define STGT   32
#define NVSRC  96
#define NVTGT  128
#define ED     128
#define HD     512
#define G4     2048   // 4*HD
#define NBHD   ((size_t)NB * HD)

typedef __attribute__((ext_vector_type(8))) _Float16 half8;
typedef __attribute__((ext_vector_type(4))) float fx4;
typedef __attribute__((ext_vector_type(4))) int intx4;

#define AS_G __attribute__((address_space(1)))
#define AS_L __attribute__((address_space(3)))

__device__ __forceinline__ void gl2lds16(const void* g, void* l) {
    // async global->LDS DMA, 16B/lane; LDS dest = wave-uniform base + lane*16
    __builtin_amdgcn_global_load_lds((const AS_G uint32_t*)g, (AS_L uint32_t*)l, 16, 0, 0);
}

__device__ __forceinline__ float sigf(float x) { return 1.0f / (1.0f + __expf(-x)); }
__device__ __forceinline__ float tanhfast(float x) { return 1.0f - 2.0f / (__expf(2.0f * x) + 1.0f); }

__global__ void convert_half(const float* __restrict__ src, int n, _Float16* __restrict__ dst) {
    int i = blockIdx.x * 256 + threadIdx.x;
    if (i < n) dst[i] = (_Float16)src[i];
}

// 32x32 LDS-tiled transpose: outT[c][r] = in[r][c]; both sides coalesced.
__global__ __launch_bounds__(256) void transpose_f32(
    const float* __restrict__ in, float* __restrict__ outT, int R, int C, int rtiles)
{
    __shared__ float ls[32][33];
    const int bx = (int)blockIdx.x % rtiles;     // r-tile
    const int by = (int)blockIdx.x / rtiles;     // c-tile
    const int tx = threadIdx.x & 31, ty = threadIdx.x >> 5;   // ty 0..7
    #pragma unroll
    for (int i = 0; i < 4; i++) {
        int rr = ty + i * 8;
        ls[rr][tx] = in[(size_t)(bx * 32 + rr) * C + by * 32 + tx];
    }
    __syncthreads();
    #pragma unroll
    for (int i = 0; i < 4; i++) {
        int rr = ty + i * 8;
        outT[(size_t)(by * 32 + rr) * R + bx * 32 + tx] = ls[tx][rr];
    }
}

// proj[v][g] = emb[v,:]·Wih[g,:] + bih[g] + bhh[g], using WT[e][g] (coalesced).
__global__ __launch_bounds__(256) void build_tables3(
    const float* __restrict__ emb, const float* __restrict__ WT,
    const float* __restrict__ bih, const float* __restrict__ bhh,
    float* __restrict__ proj)
{
    __shared__ float embL[8][ED];
    const int gc = (int)blockIdx.x & 7;
    const int vc = (int)blockIdx.x >> 3;
    const int g  = gc * 256 + threadIdx.x;
    for (int i = threadIdx.x; i < 8 * ED; i += 256)
        embL[i >> 7][i & (ED - 1)] = emb[(size_t)(vc * 8 + (i >> 7)) * ED + (i & (ED - 1))];
    __syncthreads();
    float acc[8] = {0, 0, 0, 0, 0, 0, 0, 0};
    for (int e = 0; e < ED; e++) {
        float w = WT[(size_t)e * G4 + g];
        #pragma unroll
        for (int v = 0; v < 8; v++) acc[v] += embL[v][e] * w;
    }
    float bb = bih[g] + bhh[g];
    #pragma unroll
    for (int v = 0; v < 8; v++)
        proj[(size_t)(vc * 8 + v) * G4 + g] = acc[v] + bb;
}

// Multi-step LSTM. 1024 blocks = 4/CU (24KB LDS, launch_bounds(256,4)); all
// co-resident (verified structure: R11/R12 spin kernels passed). Gate GEMM
// 128m x 64n per block + fused cell epilogue, identical math to R10.
// h slots: [row][hcol] row-major as in R10. Slot schedule per header.
template <int IS_ENC>
__global__ __launch_bounds__(256, 4) void lstm_multi(
    _Float16* __restrict__ slots, float* __restrict__ c_state,
    const float* __restrict__ proj,
    const int* __restrict__ seq, const int* __restrict__ lens,
    const _Float16* __restrict__ W,
    unsigned int* __restrict__ cnt,   // [64][32] arrival counters
    int t0, int nsteps)
{
    __shared__ __align__(16) _Float16 lsA[128 * 64];   // 16 KB
    __shared__ __align__(16) _Float16 lsB[64 * 64];    // 8 KB (also h bounce)

    const int tid = threadIdx.x;
    const int lane = tid & 63;
    const int wid  = tid >> 6;
    const int srow = lane >> 3;                    // staging row-in-group
    const int skc  = (((lane & 7) ^ srow)) << 3;   // XOR-swizzled k-chunk
    const int wm   = wid * 32;                     // wave m-offset (0..96)
    const int quad = lane >> 4;
    const int l15  = lane & 15;

    // XCD swizzle (R10) + CU-skew: m-idx = ((j&15)+(j>>5))&15 so a CU's 4
    // resident blocks (likely j, j+32, j+64, j+96) hold 4 DIFFERENT chains.
    const int x = (int)blockIdx.x & 7, j = (int)blockIdx.x >> 3;
    const int mt = (x & 1) * 16 + (((j & 15) + (j >> 5)) & 15);  // m-tile 0..31
    const int m0 = mt * 128;
    const int c0 = ((x >> 1) * 8 + (j >> 4)) * 16;               // hcol tile
    const int hcol = c0 + l15;

    // A-staging row offsets (into a slot) and B pointers
    size_t aoffA[4];
    #pragma unroll
    for (int i = 0; i < 4; i++) {
        int lr = wid * 32 + i * 8 + srow;              // local A row 0..127
        aoffA[i] = (size_t)(m0 + lr) * HD + skc;
    }
    const _Float16* bg[2];
    #pragma unroll
    for (int i = 0; i < 2; i++) {
        int lr = wid * 16 + i * 8 + srow;              // local B row 0..63
        int wr = (lr >> 4) * HD + c0 + (lr & 15);
        bg[i] = W + (size_t)wr * HD + skc;
    }

    // persistent per-lane cell state: 8 cells at (row(mf,r), hcol)
    float creg[2][4];
    _Float16 hreg[2][4];
    int lenreg[2][4];
    {
        const _Float16* hprev = (IS_ENC && t0 > 0)
            ? slots + (size_t)((t0 - 1) % 12) * NBHD : nullptr;
        #pragma unroll
        for (int mf = 0; mf < 2; mf++)
            #pragma unroll
            for (int r = 0; r < 4; r++) {
                int row = m0 + wm + mf * 16 + quad * 4 + r;
                creg[mf][r] = c_state[(size_t)row * HD + hcol];
                hreg[mf][r] = hprev ? hprev[(size_t)row * HD + hcol]
                                    : (_Float16)0.0f;
                if (IS_ENC) lenreg[mf][r] = lens[row];
            }
    }

    for (int s = 0; s < nsteps; s++) {
        const int t = t0 + s;
        const int gstep = IS_ENC ? t : 32 + t;
        const _Float16* h_r;
        _Float16* h_w;
        if (IS_ENC) {
            h_r = (t == 0) ? nullptr : slots + (size_t)((t - 1) % 12) * NBHD;
            h_w = slots + (size_t)(t % 12) * NBHD;
        } else {
            h_r = slots + (size_t)((t == 0) ? 7 : ((t - 1) % 10)) * NBHD;
            h_w = slots + (size_t)(t % 10) * NBHD;
        }

        // ---- wait: all 32 same-chain blocks finished step t-1 (first step
        // of a launch needs no wait: previous launch is stream-ordered).
        if (s > 0) {
            if (tid == 0) {
                const unsigned int* f = cnt + (size_t)(gstep - 1) * 32 + mt;
                while (__hip_atomic_load(f, __ATOMIC_RELAXED,
                                         __HIP_MEMORY_SCOPE_AGENT) < 32u)
                    __builtin_amdgcn_s_sleep(1);
            }
            __syncthreads();
            asm volatile("" ::: "memory");   // keep h loads below the spin
        }

        fx4 acc[2][4];
        #pragma unroll
        for (int i = 0; i < 2; i++)
            #pragma unroll
            for (int jj = 0; jj < 4; jj++)
                acc[i][jj] = fx4{0.f, 0.f, 0.f, 0.f};

        if (!(IS_ENC && t == 0)) {           // enc t=0: h==0, skip GEMM
            for (int k0 = 0; k0 < HD; k0 += 64) {
                __syncthreads();             // prev iter's LDS reads done
                #pragma unroll
                for (int i = 0; i < 4; i++)  // A: fresh slot, L2-cold -> L3
                    gl2lds16(h_r + aoffA[i] + k0, &lsA[(wid * 32 + i * 8) * 64]);
                #pragma unroll
                for (int i = 0; i < 2; i++)  // B: immutable, L2-resident
                    gl2lds16(bg[i] + k0, &lsB[(wid * 16 + i * 8) * 64]);
                __syncthreads();
                #pragma unroll
                for (int kk = 0; kk < 64; kk += 32) {
                    const int kc = (kk >> 3) + quad;
                    half8 af[2], bf[4];
                    #pragma unroll
                    for (int mf = 0; mf < 2; mf++) {
                        int ar = wm + mf * 16 + l15;
                        int sw = ((kc ^ (ar & 7)) << 3);
                        af[mf] = *(const half8*)&lsA[ar * 64 + sw];
                    }
                    #pragma unroll
                    for (int g = 0; g < 4; g++) {
                        int br = g * 16 + l15;
                        int sw = ((kc ^ (br & 7)) << 3);
                        bf[g] = *(const half8*)&lsB[br * 64 + sw];
                    }
                    #pragma unroll
                    for (int mf = 0; mf < 2; mf++)
                        #pragma unroll
                        for (int g = 0; g < 4; g++)
                            acc[mf][g] = __builtin_amdgcn_mfma_f32_16x16x32_f16(
                                af[mf], bf[g], acc[mf][g], 0, 0, 0);
                }
            }
        }

        // ---- fused cell epilogue (identical math to R10), h via LDS bounce
        __syncthreads();                      // lsA/lsB frag reads done
        _Float16* htile = lsB;                // [128][16]
        #pragma unroll
        for (int mf = 0; mf < 2; mf++) {
            #pragma unroll
            for (int r = 0; r < 4; r++) {
                const int lrow = wm + mf * 16 + quad * 4 + r;
                const int row = m0 + lrow;
                int tok;
                if (IS_ENC) tok = seq[row * SSRC + t];
                else        tok = (t == 0) ? 1 : seq[row * STGT + t - 1]; // SOS=1
                const float* xp = proj + (size_t)tok * G4 + hcol;
                float gi = acc[mf][0][r] + xp[0];
                float gf = acc[mf][1][r] + xp[HD];
                float gg = acc[mf][2][r] + xp[2 * HD];
                float go = acc[mf][3][r] + xp[3 * HD];
                float ii = sigf(gi), ff = sigf(gf), oo = sigf(go);
                float g2 = tanhfast(gg);
                float cold = creg[mf][r];
                float c2 = ff * cold + ii * g2;
                _Float16 h2 = (_Float16)(oo * tanhfast(c2));
                if (IS_ENC && t >= lenreg[mf][r]) {   // pack_padded semantics
                    c2 = cold;
                    h2 = hreg[mf][r];                  // exact fp16 carry
                }
                creg[mf][r] = c2;
                if (IS_ENC) hreg[mf][r] = h2;
                htile[lrow * 16 + l15] = h2;
            }
        }
        __syncthreads();
        {   // coalesced write-through to L3: 16B/thread, sc0+sc1
            const int lrow = tid >> 1, cof = (tid & 1) * 8;
            intx4 v = *(const intx4*)&htile[lrow * 16 + cof];
            unsigned long long dp = (unsigned long long)(uintptr_t)
                (h_w + (size_t)(m0 + lrow) * HD + c0 + cof);
            asm volatile("global_store_dwordx4 %0, %1, off sc0 sc1"
                         :: "v"(dp), "v"(v) : "memory");
        }
        asm volatile("s_waitcnt vmcnt(0)" ::: "memory");
        // ---- arrive: RELEASE atomic (wbl2 belt+suspenders) per block
        if (s < nsteps - 1) {
            __syncthreads();
            if (tid == 0)
                __hip_atomic_fetch_add(cnt + (size_t)gstep * 32 + mt, 1u,
                                       __ATOMIC_RELEASE,
                                       __HIP_MEMORY_SCOPE_AGENT);
        }
    }

    // c writeback for next launch (kernel-end flush makes it visible)
    #pragma unroll
    for (int mf = 0; mf < 2; mf++)
        #pragma unroll
        for (int r = 0; r < 4; r++) {
            int row = m0 + wm + mf * 16 + quad * 4 + r;
            c_state[(size_t)row * HD + hcol] = creg[mf][r];
        }
}

// Batched outproj: 256 blocks = (8 t) x (32 m-tiles), each 128x128x512.
__global__ __launch_bounds__(256, 2) void outproj_batch(
    const _Float16* __restrict__ h_slots, int t0,
    const _Float16* __restrict__ Wo, const float* __restrict__ bout,
    float* __restrict__ out)
{
    __shared__ __align__(16) _Float16 lsA[128 * 64];
    __shared__ __align__(16) _Float16 lsB[128 * 64];

    const int tid = threadIdx.x;
    const int lane = tid & 63;
    const int wid  = tid >> 6;
    const int srow = lane >> 3;
    const int skc  = (((lane & 7) ^ srow)) << 3;
    const int wm    = (wid >> 1) * 64;
    const int wncol = wid & 1;
    const int quad  = lane >> 4;
    const int l15   = lane & 15;
    const int bsw   = (l15 & 7);

    const int t  = t0 + ((int)blockIdx.x >> 5);
    const int m0 = ((int)blockIdx.x & 31) * 128;
    const _Float16* h_r = h_slots + (size_t)(t % 10) * NBHD;

    const _Float16 *ag[4], *bg[4];
    #pragma unroll
    for (int i = 0; i < 4; i++) {
        int lr = wid * 32 + i * 8 + srow;
        ag[i] = h_r + (size_t)(m0 + lr) * HD + skc;
        bg[i] = Wo + (size_t)lr * HD + skc;   // Wout row = v
    }

    fx4 acc[4][4];
    #pragma unroll
    for (int i = 0; i < 4; i++)
        #pragma unroll
        for (int jj = 0; jj < 4; jj++)
            acc[i][jj] = fx4{0.f, 0.f, 0.f, 0.f};

    for (int k0 = 0; k0 < HD; k0 += 64) {
        __syncthreads();
        #pragma unroll
        for (int i = 0; i < 4; i++) {
            int lb = (wid * 32 + i * 8) * 64;
            gl2lds16(ag[i] + k0, &lsA[lb]);
            gl2lds16(bg[i] + k0, &lsB[lb]);
        }
        __syncthreads();
        #pragma unroll
        for (int kk = 0; kk < 64; kk += 32) {
            const int kc = (kk >> 3) + quad;
            const int sw = ((kc ^ bsw) << 3);
            half8 af[4], bf[4];
            #pragma unroll
            for (int mt = 0; mt < 4; mt++)
                af[mt] = *(const half8*)&lsA[(wm + mt * 16 + l15) * 64 + sw];
            #pragma unroll
            for (int nt = 0; nt < 4; nt++)
                bf[nt] = *(const half8*)&lsB[(wncol * 64 + nt * 16 + l15) * 64 + sw];
            #pragma unroll
            for (int mt = 0; mt < 4; mt++)
                #pragma unroll
                for (int nt = 0; nt < 4; nt++)
                    acc[mt][nt] = __builtin_amdgcn_mfma_f32_16x16x32_f16(af[mt], bf[nt], acc[mt][nt], 0, 0, 0);
        }
    }

    #pragma unroll
    for (int mt = 0; mt < 4; mt++)
        #pragma unroll
        for (int nt = 0; nt < 4; nt++) {
            int v = wncol * 64 + nt * 16 + l15;
            float bo = bout[v];
            #pragma unroll
            for (int r = 0; r < 4; r++) {
                int row = m0 + wm + mt * 16 + quad * 4 + r;
                out[((size_t)row * STGT + t) * NVTGT + v] = acc[mt][nt][r] + bo;
            }
        }
}

extern "C" void kernel_launch(void* const* d_in, const int* in_sizes, int n_in,
                              void* d_out, int out_size, void* d_ws, size_t ws_size,
                              hipStream_t stream) {
    (void)in_sizes; (void)n_in; (void)out_size; (void)ws_size;
    const int* src_seq = (const int*)d_in[0];
    const int* src_len = (const int*)d_in[1];
    const int* tgt_seq = (const int*)d_in[2];
    const float* emb_src = (const float*)d_in[3];
    const float* eWih = (const float*)d_in[4];
    const float* eWhh = (const float*)d_in[5];
    const float* ebih = (const float*)d_in[6];
    const float* ebhh = (const float*)d_in[7];
    const float* emb_tgt = (const float*)d_in[8];
    const float* dWih = (const float*)d_in[9];
    const float* dWhh = (const float*)d_in[10];
    const float* dbih = (const float*)d_in[11];
    const float* dbhh = (const float*)d_in[12];
    const float* Wout = (const float*)d_in[13];
    const float* bout = (const float*)d_in[14];
    float* out = (float*)d_out;

    char* ws = (char*)d_ws;
    size_t off = 0;
    auto carve = [&](size_t bytes) { void* p = ws + off; off += (bytes + 255) & ~(size_t)255; return p; };
    float* proj_src = (float*)carve((size_t)NVSRC * G4 * 4);
    float* proj_tgt = (float*)carve((size_t)NVTGT * G4 * 4);
    float* c_state  = (float*)carve(NBHD * 4);
    _Float16* slots = (_Float16*)carve((size_t)12 * NBHD * 2);   // 48 MB
    _Float16* eW_h  = (_Float16*)carve((size_t)G4 * HD * 2);
    _Float16* dW_h  = (_Float16*)carve((size_t)G4 * HD * 2);
    _Float16* Wo_h  = (_Float16*)carve((size_t)NVTGT * HD * 2);
    unsigned int* cnt = (unsigned int*)carve((size_t)64 * 32 * 4); // arrivals
    // WT buffers alias slot 0 (overwritten first at enc step 0, long after
    // the tables are built). 1 MB each, slot is 4 MB.
    float* WT_e = (float*)(slots);
    float* WT_d = (float*)((char*)slots + (size_t)ED * G4 * 4);

    hipMemsetAsync(c_state, 0, NBHD * 4, stream);
    hipMemsetAsync(cnt, 0, (size_t)64 * 32 * 4, stream);

    convert_half<<<dim3(G4 * HD / 256), dim3(256), 0, stream>>>(eWhh, G4 * HD, eW_h);
    convert_half<<<dim3(G4 * HD / 256), dim3(256), 0, stream>>>(dWhh, G4 * HD, dW_h);
    convert_half<<<dim3(NVTGT * HD / 256), dim3(256), 0, stream>>>(Wout, NVTGT * HD, Wo_h);
    transpose_f32<<<dim3((G4 / 32) * (ED / 32)), dim3(256), 0, stream>>>(eWih, WT_e, G4, ED, G4 / 32);
    transpose_f32<<<dim3((G4 / 32) * (ED / 32)), dim3(256), 0, stream>>>(dWih, WT_d, G4, ED, G4 / 32);
    build_tables3<<<dim3((NVSRC / 8) * 8), dim3(256), 0, stream>>>(emb_src, WT_e, ebih, ebhh, proj_src);
    build_tables3<<<dim3((NVTGT / 8) * 8), dim3(256), 0, stream>>>(emb_tgt, WT_d, dbih, dbhh, proj_tgt);

    // encoder: 3 multi-step launches (12-slot freshness window);
    // enc step t writes slot t%12, final h (t=31) lands in slot 7.
    lstm_multi<1><<<dim3(1024), dim3(256), 0, stream>>>(
        slots, c_state, proj_src, src_seq, src_len, eW_h, cnt, 0, 12);
    lstm_multi<1><<<dim3(1024), dim3(256), 0, stream>>>(
        slots, c_state, proj_src, src_seq, src_len, eW_h, cnt, 12, 12);
    lstm_multi<1><<<dim3(1024), dim3(256), 0, stream>>>(
        slots, c_state, proj_src, src_seq, src_len, eW_h, cnt, 24, 8);
    // decoder: 4 multi-step launches of 8 (ring-10; t=0 reads enc slot 7),
    // outproj after each batch of 8 as before.
    for (int k = 0; k < 4; k++) {
        lstm_multi<0><<<dim3(1024), dim3(256), 0, stream>>>(
            slots, c_state, proj_tgt, tgt_seq, nullptr, dW_h, cnt, k * 8, 8);
        outproj_batch<<<dim3(256), dim3(256), 0, stream>>>(
            slots, k * 8, Wo_h, bout, out);
    }
}

// Round 5
// 1458.134 us; speedup vs baseline: 4.6674x; 4.6674x over previous
//
#include <hip/hip_runtime.h>
#include <hip/hip_bf16.h>
#include <hip/hip_fp16.h>
#include <stdint.h>

// Seq2Seq LSTM: B=4096, H=512, E=128, 32 enc + 32 dec steps, V_tgt=128.
// Round 15: LENGTH-SORTED ENCODER EARLY-EXIT + FLOAT4 PROJ TABLE.
// R11/R12/R14 proved intra-kernel chain barriers convoy (56-109 us/step vs
// 23 us with per-step launches); R13 proved in-kernel pipelining is null.
// So: keep the proven R10 per-step-launch structure and (a) do less work,
// (b) make the epilogue leaner:
//  - rows are independent chains -> process in LENGTH-SORTED order
//    (device counting sort). Sorted m-tile i has maxlen~i+1; encoder blocks
//    early-exit when t >= maxlen[mt]: ~48% of encoder GEMM work skipped.
//  - row finals: at t+1==len the epilogue writes h2 to hfinal (bitwise the
//    value R10 chain-carried to slot 10); c_state retains final c when
//    writes stop. Decoder t=0 reads hfinal.
//  - proj table gate-contiguous [tok][hcol][4]: 1 float4 load per cell
//    instead of 4 stride-512 scalar loads.
// Per-row math identical & permutation-invariant -> absmax unchanged.

#define NB     4096
#define SSRC   32
#define STGT   32
#define NVSRC  96
#define NVTGT  128
#define ED     128
#define HD     512
#define G4     2048   // 4*HD
#define NBHD   ((size_t)NB * HD)

typedef __attribute__((ext_vector_type(8))) _Float16 half8;
typedef __attribute__((ext_vector_type(4))) float fx4;

#define AS_G __attribute__((address_space(1)))
#define AS_L __attribute__((address_space(3)))

__device__ __forceinline__ void gl2lds16(const void* g, void* l) {
    // async global->LDS DMA, 16B/lane; LDS dest = wave-uniform base + lane*16
    __builtin_amdgcn_global_load_lds((const AS_G uint32_t*)g, (AS_L uint32_t*)l, 16, 0, 0);
}

__device__ __forceinline__ float sigf(float x) { return 1.0f / (1.0f + __expf(-x)); }
__device__ __forceinline__ float tanhfast(float x) { return 1.0f - 2.0f / (__expf(2.0f * x) + 1.0f); }

__global__ void convert_half(const float* __restrict__ src, int n, _Float16* __restrict__ dst) {
    int i = blockIdx.x * 256 + threadIdx.x;
    if (i < n) dst[i] = (_Float16)src[i];
}

// 32x32 LDS-tiled transpose: outT[c][r] = in[r][c]; both sides coalesced.
__global__ __launch_bounds__(256) void transpose_f32(
    const float* __restrict__ in, float* __restrict__ outT, int R, int C, int rtiles)
{
    __shared__ float ls[32][33];
    const int bx = (int)blockIdx.x % rtiles;     // r-tile
    const int by = (int)blockIdx.x / rtiles;     // c-tile
    const int tx = threadIdx.x & 31, ty = threadIdx.x >> 5;   // ty 0..7
    #pragma unroll
    for (int i = 0; i < 4; i++) {
        int rr = ty + i * 8;
        ls[rr][tx] = in[(size_t)(bx * 32 + rr) * C + by * 32 + tx];
    }
    __syncthreads();
    #pragma unroll
    for (int i = 0; i < 4; i++) {
        int rr = ty + i * 8;
        outT[(size_t)(by * 32 + rr) * R + bx * 32 + tx] = ls[tx][rr];
    }
}

// proj[v][hcol][gate] = emb[v,:]·Wih[g,:] + bih[g] + bhh[g]  (gate-contig!)
// g = gate*HD + hcol in the original gate-major index space.
__global__ __launch_bounds__(256) void build_tables3(
    const float* __restrict__ emb, const float* __restrict__ WT,
    const float* __restrict__ bih, const float* __restrict__ bhh,
    float* __restrict__ proj)
{
    __shared__ float embL[8][ED];
    const int gc = (int)blockIdx.x & 7;
    const int vc = (int)blockIdx.x >> 3;
    const int g  = gc * 256 + threadIdx.x;
    for (int i = threadIdx.x; i < 8 * ED; i += 256)
        embL[i >> 7][i & (ED - 1)] = emb[(size_t)(vc * 8 + (i >> 7)) * ED + (i & (ED - 1))];
    __syncthreads();
    float acc[8] = {0, 0, 0, 0, 0, 0, 0, 0};
    for (int e = 0; e < ED; e++) {
        float w = WT[(size_t)e * G4 + g];
        #pragma unroll
        for (int v = 0; v < 8; v++) acc[v] += embL[v][e] * w;
    }
    float bb = bih[g] + bhh[g];
    const int gate = g >> 9, hcol = g & (HD - 1);
    #pragma unroll
    for (int v = 0; v < 8; v++)
        proj[(((size_t)(vc * 8 + v) * HD + hcol) << 2) + gate] = acc[v] + bb;
}

// Counting sort of rows by src length (keys 1..32). Single block.
// perm[sorted_pos] = orig_row; lens_s sorted lengths; maxlen per 128-row tile.
__global__ __launch_bounds__(256) void sort_rows(
    const int* __restrict__ lens, int* __restrict__ perm,
    int* __restrict__ lens_s, int* __restrict__ maxlen)
{
    __shared__ int hist[33];
    __shared__ int base[33];
    const int tid = threadIdx.x;
    if (tid < 33) hist[tid] = 0;
    __syncthreads();
    for (int i = tid; i < NB; i += 256) atomicAdd(&hist[lens[i]], 1);
    __syncthreads();
    if (tid == 0) {
        int s = 0;
        for (int l = 1; l <= 32; l++) { base[l] = s; s += hist[l]; }
    }
    __syncthreads();
    for (int i = tid; i < NB; i += 256) {
        int l = lens[i];
        int pos = atomicAdd(&base[l], 1);
        perm[pos] = i;
        lens_s[pos] = l;
    }
    __syncthreads();
    if (tid < 32) maxlen[tid] = lens_s[tid * 128 + 127];
}

// seq_s[sorted_row][t] = seq[perm[sorted_row]][t], S=32.
__global__ __launch_bounds__(256) void gather_seq(
    const int* __restrict__ seq, const int* __restrict__ perm,
    int* __restrict__ seq_s)
{
    int i = (int)blockIdx.x * 256 + threadIdx.x;   // over NB*32
    int row = i >> 5, t = i & 31;
    seq_s[i] = seq[perm[row] * 32 + t];
}

// Gate GEMM, 128m x 64n (4 gates x 16 hcols) per block + fused cell epilogue.
// 1024 blocks = 4 blocks/CU (16 waves/CU). All rows in SORTED space.
__global__ __launch_bounds__(256, 4) void lstm_step(
    const _Float16* __restrict__ h_r, _Float16* __restrict__ h_w,
    float* __restrict__ c_state,
    const float* __restrict__ proj,      // [tok][hcol][4]
    const int* __restrict__ seq_s, const int* __restrict__ lens_s,
    const int* __restrict__ maxlen,
    const _Float16* __restrict__ W,
    _Float16* __restrict__ hfinal,
    int t, int is_enc, int skip_gemm)
{
    __shared__ __align__(16) _Float16 lsA[128 * 64];   // 16 KB
    __shared__ __align__(16) _Float16 lsB[64 * 64];    // 8 KB

    const int tid = threadIdx.x;
    const int lane = tid & 63;
    const int wid  = tid >> 6;
    const int srow = lane >> 3;                    // staging row-in-group
    const int skc  = (((lane & 7) ^ srow)) << 3;   // XOR-swizzled k-chunk
    const int wm   = wid * 32;                     // wave m-offset (0..96)
    const int quad = lane >> 4;
    const int l15  = lane & 15;

    // XCD swizzle: per-XCD ws = 16 m-tiles (2 MB A) + 8 hcol-tiles (0.5 MB B)
    const int x = (int)blockIdx.x & 7, j = (int)blockIdx.x >> 3;
    const int mt = (x & 1) * 16 + (j & 15);            // m-tile (sorted space)
    const int m0 = mt * 128;
    const int c0 = ((x >> 1) * 8 + (j >> 4)) * 16;     // hcol tile (32 total)

    // whole tile frozen: every row already wrote hfinal; c_state holds finals
    if (is_enc && t >= maxlen[mt]) return;

    const _Float16 *ag[4], *bg[2];
    #pragma unroll
    for (int i = 0; i < 4; i++) {
        int lr = wid * 32 + i * 8 + srow;              // local A row 0..127
        ag[i] = h_r + (size_t)(m0 + lr) * HD + skc;
    }
    #pragma unroll
    for (int i = 0; i < 2; i++) {
        int lr = wid * 16 + i * 8 + srow;              // local B row 0..63
        int wr = (lr >> 4) * HD + c0 + (lr & 15);      // gate=lr>>4, tcol=lr&15
        bg[i] = W + (size_t)wr * HD + skc;
    }

    fx4 acc[2][4];
    #pragma unroll
    for (int i = 0; i < 2; i++)
        #pragma unroll
        for (int jj = 0; jj < 4; jj++)
            acc[i][jj] = fx4{0.f, 0.f, 0.f, 0.f};

    if (!skip_gemm) {
        for (int k0 = 0; k0 < HD; k0 += 64) {
            __syncthreads();
            #pragma unroll
            for (int i = 0; i < 4; i++)
                gl2lds16(ag[i] + k0, &lsA[(wid * 32 + i * 8) * 64]);
            #pragma unroll
            for (int i = 0; i < 2; i++)
                gl2lds16(bg[i] + k0, &lsB[(wid * 16 + i * 8) * 64]);
            __syncthreads();
            #pragma unroll
            for (int kk = 0; kk < 64; kk += 32) {
                const int kc = (kk >> 3) + quad;
                half8 af[2], bf[4];
                #pragma unroll
                for (int mf = 0; mf < 2; mf++) {
                    int ar = wm + mf * 16 + l15;
                    int sw = ((kc ^ (ar & 7)) << 3);
                    af[mf] = *(const half8*)&lsA[ar * 64 + sw];
                }
                #pragma unroll
                for (int g = 0; g < 4; g++) {
                    int br = g * 16 + l15;
                    int sw = ((kc ^ (br & 7)) << 3);
                    bf[g] = *(const half8*)&lsB[br * 64 + sw];
                }
                #pragma unroll
                for (int mf = 0; mf < 2; mf++)
                    #pragma unroll
                    for (int g = 0; g < 4; g++)
                        acc[mf][g] = __builtin_amdgcn_mfma_f32_16x16x32_f16(af[mf], bf[g], acc[mf][g], 0, 0, 0);
            }
        }
    }

    // fused cell epilogue: acc[mf][gate][r] — all 4 gates per (row,hcol)
    const int hcol = c0 + l15;
    #pragma unroll
    for (int mf = 0; mf < 2; mf++) {
        #pragma unroll
        for (int r = 0; r < 4; r++) {
            int row = m0 + wm + mf * 16 + quad * 4 + r;
            int tok = is_enc ? seq_s[row * SSRC + t]
                             : (t == 0 ? 1 : seq_s[row * STGT + t - 1]);  // SOS=1
            const fx4 xp = *(const fx4*)&proj[((size_t)tok * HD + hcol) << 2];
            float gi = acc[mf][0][r] + xp[0];
            float gf = acc[mf][1][r] + xp[1];
            float gg = acc[mf][2][r] + xp[2];
            float go = acc[mf][3][r] + xp[3];
            float ii = sigf(gi), ff = sigf(gf), oo = sigf(go);
            float g2 = tanhfast(gg);
            size_t off = (size_t)row * HD + hcol;
            float cold = c_state[off];
            float c2 = ff * cold + ii * g2;
            float h2 = oo * tanhfast(c2);
            if (is_enc) {
                int len = lens_s[row];
                if (t >= len) {               // pack_padded semantics
                    c2 = cold;
                    h2 = (float)h_r[off];     // exact fp16 carry
                }
                if (t + 1 == len)             // row's final h (bitwise = R10)
                    hfinal[off] = (_Float16)h2;
            }
            c_state[off] = c2;
            h_w[off] = (_Float16)h2;
        }
    }
}

// Batched outproj: 256 blocks = (8 t) x (32 m-tiles), each 128x128x512.
// Rows are in sorted space; out is scattered back through perm.
__global__ __launch_bounds__(256, 2) void outproj_batch(
    const _Float16* __restrict__ h_slots, int t0,
    const _Float16* __restrict__ Wo, const float* __restrict__ bout,
    const int* __restrict__ perm,
    float* __restrict__ out)
{
    __shared__ __align__(16) _Float16 lsA[128 * 64];
    __shared__ __align__(16) _Float16 lsB[128 * 64];

    const int tid = threadIdx.x;
    const int lane = tid & 63;
    const int wid  = tid >> 6;
    const int srow = lane >> 3;
    const int skc  = (((lane & 7) ^ srow)) << 3;
    const int wm    = (wid >> 1) * 64;
    const int wncol = wid & 1;
    const int quad  = lane >> 4;
    const int l15   = lane & 15;
    const int bsw   = (l15 & 7);

    const int t  = t0 + ((int)blockIdx.x >> 5);
    const int m0 = ((int)blockIdx.x & 31) * 128;
    const _Float16* h_r = h_slots + (size_t)(t % 10) * NBHD;

    const _Float16 *ag[4], *bg[4];
    #pragma unroll
    for (int i = 0; i < 4; i++) {
        int lr = wid * 32 + i * 8 + srow;
        ag[i] = h_r + (size_t)(m0 + lr) * HD + skc;
        bg[i] = Wo + (size_t)lr * HD + skc;   // Wout row = v
    }

    fx4 acc[4][4];
    #pragma unroll
    for (int i = 0; i < 4; i++)
        #pragma unroll
        for (int jj = 0; jj < 4; jj++)
            acc[i][jj] = fx4{0.f, 0.f, 0.f, 0.f};

    for (int k0 = 0; k0 < HD; k0 += 64) {
        __syncthreads();
        #pragma unroll
        for (int i = 0; i < 4; i++) {
            int lb = (wid * 32 + i * 8) * 64;
            gl2lds16(ag[i] + k0, &lsA[lb]);
            gl2lds16(bg[i] + k0, &lsB[lb]);
        }
        __syncthreads();
        #pragma unroll
        for (int kk = 0; kk < 64; kk += 32) {
            const int kc = (kk >> 3) + quad;
            const int sw = ((kc ^ bsw) << 3);
            half8 af[4], bf[4];
            #pragma unroll
            for (int mt = 0; mt < 4; mt++)
                af[mt] = *(const half8*)&lsA[(wm + mt * 16 + l15) * 64 + sw];
            #pragma unroll
            for (int nt = 0; nt < 4; nt++)
                bf[nt] = *(const half8*)&lsB[(wncol * 64 + nt * 16 + l15) * 64 + sw];
            #pragma unroll
            for (int mt = 0; mt < 4; mt++)
                #pragma unroll
                for (int nt = 0; nt < 4; nt++)
                    acc[mt][nt] = __builtin_amdgcn_mfma_f32_16x16x32_f16(af[mt], bf[nt], acc[mt][nt], 0, 0, 0);
        }
    }

    #pragma unroll
    for (int mt = 0; mt < 4; mt++)
        #pragma unroll
        for (int nt = 0; nt < 4; nt++) {
            int v = wncol * 64 + nt * 16 + l15;
            float bo = bout[v];
            #pragma unroll
            for (int r = 0; r < 4; r++) {
                int row = m0 + wm + mt * 16 + quad * 4 + r;   // sorted space
                int orow = perm[row];
                out[((size_t)orow * STGT + t) * NVTGT + v] = acc[mt][nt][r] + bo;
            }
        }
}

extern "C" void kernel_launch(void* const* d_in, const int* in_sizes, int n_in,
                              void* d_out, int out_size, void* d_ws, size_t ws_size,
                              hipStream_t stream) {
    (void)in_sizes; (void)n_in; (void)out_size; (void)ws_size;
    const int* src_seq = (const int*)d_in[0];
    const int* src_len = (const int*)d_in[1];
    const int* tgt_seq = (const int*)d_in[2];
    const float* emb_src = (const float*)d_in[3];
    const float* eWih = (const float*)d_in[4];
    const float* eWhh = (const float*)d_in[5];
    const float* ebih = (const float*)d_in[6];
    const float* ebhh = (const float*)d_in[7];
    const float* emb_tgt = (const float*)d_in[8];
    const float* dWih = (const float*)d_in[9];
    const float* dWhh = (const float*)d_in[10];
    const float* dbih = (const float*)d_in[11];
    const float* dbhh = (const float*)d_in[12];
    const float* Wout = (const float*)d_in[13];
    const float* bout = (const float*)d_in[14];
    float* out = (float*)d_out;

    char* ws = (char*)d_ws;
    size_t off = 0;
    auto carve = [&](size_t bytes) { void* p = ws + off; off += (bytes + 255) & ~(size_t)255; return p; };
    float* proj_src = (float*)carve((size_t)NVSRC * G4 * 4);
    float* proj_tgt = (float*)carve((size_t)NVTGT * G4 * 4);
    float* c_state  = (float*)carve(NBHD * 4);
    _Float16* slots = (_Float16*)carve((size_t)12 * NBHD * 2);   // 48 MB
    _Float16* eW_h  = (_Float16*)carve((size_t)G4 * HD * 2);
    _Float16* dW_h  = (_Float16*)carve((size_t)G4 * HD * 2);
    _Float16* Wo_h  = (_Float16*)carve((size_t)NVTGT * HD * 2);
    _Float16* hfinal = (_Float16*)carve(NBHD * 2);               // 4 MB
    int* perm   = (int*)carve((size_t)NB * 4);
    int* lens_s = (int*)carve((size_t)NB * 4);
    int* maxlen = (int*)carve(32 * 4);
    int* src_s  = (int*)carve((size_t)NB * SSRC * 4);
    int* tgt_s  = (int*)carve((size_t)NB * STGT * 4);
    // WT buffers alias decoder slot 0 (first written at decoder step 0,
    // long after tables are built). 1 MB each, slot is 4 MB.
    float* WT_e = (float*)(slots);
    float* WT_d = (float*)((char*)slots + (size_t)ED * G4 * 4);
    auto slot = [&](int i) { return slots + (size_t)i * NBHD; };

    hipMemsetAsync(c_state, 0, NBHD * 4, stream);

    sort_rows<<<dim3(1), dim3(256), 0, stream>>>(src_len, perm, lens_s, maxlen);
    gather_seq<<<dim3(NB * SSRC / 256), dim3(256), 0, stream>>>(src_seq, perm, src_s);
    gather_seq<<<dim3(NB * STGT / 256), dim3(256), 0, stream>>>(tgt_seq, perm, tgt_s);

    convert_half<<<dim3(G4 * HD / 256), dim3(256), 0, stream>>>(eWhh, G4 * HD, eW_h);
    convert_half<<<dim3(G4 * HD / 256), dim3(256), 0, stream>>>(dWhh, G4 * HD, dW_h);
    convert_half<<<dim3(NVTGT * HD / 256), dim3(256), 0, stream>>>(Wout, NVTGT * HD, Wo_h);
    transpose_f32<<<dim3((G4 / 32) * (ED / 32)), dim3(256), 0, stream>>>(eWih, WT_e, G4, ED, G4 / 32);
    transpose_f32<<<dim3((G4 / 32) * (ED / 32)), dim3(256), 0, stream>>>(dWih, WT_d, G4, ED, G4 / 32);
    build_tables3<<<dim3((NVSRC / 8) * 8), dim3(256), 0, stream>>>(emb_src, WT_e, ebih, ebhh, proj_src);
    build_tables3<<<dim3((NVTGT / 8) * 8), dim3(256), 0, stream>>>(emb_tgt, WT_d, dbih, dbhh, proj_tgt);

    // encoder: slots 10/11 alternate; s=0 skips GEMM (h==0, mask never
    // reads h_r at t=0 since len>=1). Finals land in hfinal/c_state.
    for (int s = 0; s < 32; s++) {
        lstm_step<<<dim3(1024), dim3(256), 0, stream>>>(
            slot(10 + (s & 1)), slot(10 + ((s + 1) & 1)), c_state,
            proj_src, src_s, lens_s, maxlen, eW_h, hfinal, s, 1, (s == 0));
    }
    // decoder: 10-slot ring (slot = t mod 10); t=0 reads hfinal.
    for (int t = 0; t < 32; t++) {
        const _Float16* hr = (t == 0) ? hfinal : slot((t - 1) % 10);
        lstm_step<<<dim3(1024), dim3(256), 0, stream>>>(
            hr, slot(t % 10), c_state,
            proj_tgt, tgt_s, lens_s, maxlen, dW_h, hfinal, t, 0, 0);
        if ((t & 7) == 7) {
            outproj_batch<<<dim3(256), dim3(256), 0, stream>>>(
                slots, t - 7, Wo_h, bout, perm, out);
        }
    }
}